// Round 5
// baseline (2758.353 us; speedup 1.0000x reference)
//
#include <hip/hip_runtime.h>
#include <hip/hip_bf16.h>
#include <math.h>

// Problem constants (from reference):
//   B=128, S=1024, D1=64 (SIZE1), N=2048, D0=512 (SIZE0)
#define B_   128
#define S_   1024
#define D1_  64
#define N_   2048
#define D0_  512

// R0 logits geometry (empirically fastest stream): block = 256 thr = 4 waves,
// one row per wave, 65536 one-shot blocks, 512 blocks per batch.
#define BLOCKS_PER_BATCH 512

// -----------------------------------------------------------------------------
// Kernel 0: v[b,s] = sum_d enc[b, current_index, d] * W[d, s]
// Bias dropped: adds a per-row constant to logits -> cancels in softmax.
// Also zeroes this batch's completion counter for the fused softmax
// (d_ws is poisoned 0xAA once and never re-poisoned; we must re-zero every
// call to stay deterministic across graph replays).
// -----------------------------------------------------------------------------
__global__ __launch_bounds__(D0_) void prep_kernel(
    const float* __restrict__ enc, const int* __restrict__ cur_idx,
    const float* __restrict__ W, float* __restrict__ v,
    unsigned int* __restrict__ cnt)
{
    __shared__ float temp[D1_];
    const int b = blockIdx.x;
    const int t = threadIdx.x;           // 0..511
    const int ci = *cur_idx;
    if (t == 0) cnt[b] = 0u;             // reset finisher counter each call
    if (t < D1_) {
        temp[t] = enc[(size_t)b * (S_ * D1_) + (size_t)ci * D1_ + t];
    }
    __syncthreads();
    float acc = 0.f;
#pragma unroll
    for (int d = 0; d < D1_; ++d) {
        acc += temp[d] * W[d * D0_ + t];
    }
    v[b * D0_ + t] = acc;
}

// -----------------------------------------------------------------------------
// Kernel 1 (fused): logits + per-batch softmax finisher.
// Stream part is EXACTLY R0 (fastest measured): one 64-lane wave per row,
// 2 coalesced float4 nb loads + 2 L2-hit v loads, 8 FMAs, 6-step butterfly,
// lane-0 store. Then each block signals completion of its batch; the 512th
// block to finish a batch performs that batch's 2048-wide softmax in-place
// (lookback-scan pattern: release fence + atomic, acquire fence + read).
// Softmax overlaps the tail of the stream and removes one kernel launch +
// one full-grid drain.
// -----------------------------------------------------------------------------
__global__ __launch_bounds__(256) void logits_fused_kernel(
    const float* __restrict__ nb, const float* __restrict__ v,
    float* __restrict__ out, unsigned int* __restrict__ cnt)
{
    const int wave = threadIdx.x >> 6;          // 0..3
    const int lane = threadIdx.x & 63;
    const size_t row = (size_t)blockIdx.x * 4 + wave;   // 0 .. B_*N_-1
    const int b = blockIdx.x >> 9;              // batch (block-uniform)

    const float4* __restrict__ r  = (const float4*)(nb + row * D0_);
    const float4* __restrict__ vv = (const float4*)(v + (size_t)b * D0_);

    float4 r0 = r[lane];
    float4 r1 = r[lane + 64];
    float4 v0 = vv[lane];
    float4 v1 = vv[lane + 64];

    float s = r0.x * v0.x + r0.y * v0.y + r0.z * v0.z + r0.w * v0.w
            + r1.x * v1.x + r1.y * v1.y + r1.z * v1.z + r1.w * v1.w;

#pragma unroll
    for (int off = 32; off; off >>= 1) s += __shfl_xor(s, off);

    if (lane == 0) out[row] = s;

    // ---- completion protocol ----
    __shared__ unsigned int prev;
    __syncthreads();                            // all 4 stores issued
    if (threadIdx.x == 0) {
        __threadfence();                        // release: logits visible device-wide
        prev = atomicAdd(&cnt[b], 1u);
    }
    __syncthreads();
    if (prev != BLOCKS_PER_BATCH - 1) return;   // not the last block of batch b

    // ---- finisher: softmax over out[b*N_ .. b*N_+N_) ----
    __threadfence();                            // acquire: see all batch logits
    float* rowp = out + (size_t)b * N_;
    const int t = threadIdx.x;
    const int w2 = t >> 6, l2 = t & 63;

    float vals[8];
    float m = -INFINITY;
#pragma unroll
    for (int i = 0; i < 8; ++i) {
        vals[i] = rowp[t + i * 256];
        m = fmaxf(m, vals[i]);
    }
#pragma unroll
    for (int off = 32; off; off >>= 1) m = fmaxf(m, __shfl_xor(m, off));

    __shared__ float redm[4];
    __shared__ float reds[4];
    if (l2 == 0) redm[w2] = m;
    __syncthreads();
    m = fmaxf(fmaxf(redm[0], redm[1]), fmaxf(redm[2], redm[3]));

    float sum = 0.f;
#pragma unroll
    for (int i = 0; i < 8; ++i) {
        vals[i] = __expf(vals[i] - m);
        sum += vals[i];
    }
#pragma unroll
    for (int off = 32; off; off >>= 1) sum += __shfl_xor(sum, off);
    if (l2 == 0) reds[w2] = sum;
    __syncthreads();
    sum = reds[0] + reds[1] + reds[2] + reds[3];

    const float inv = 1.0f / sum;
#pragma unroll
    for (int i = 0; i < 8; ++i) rowp[t + i * 256] = vals[i] * inv;
}

extern "C" void kernel_launch(void* const* d_in, const int* in_sizes, int n_in,
                              void* d_out, int out_size, void* d_ws, size_t ws_size,
                              hipStream_t stream)
{
    // Input order per setup_inputs():
    //   0: encoder_outputs          (B,S,D1) f32
    //   1: current_index            scalar int
    //   2: encoder_outputs_neighbor (B,N,D0) f32
    //   3: neighbor_num             scalar int (== N_, unused)
    //   4: W                        (D1,D0) f32
    //   5: b                        (D1,) f32  -- cancels in softmax, unused
    const float* enc     = (const float*)d_in[0];
    const int*   cur_idx = (const int*)d_in[1];
    const float* nb      = (const float*)d_in[2];
    const float* W       = (const float*)d_in[4];
    float*       out     = (float*)d_out;
    float*       v       = (float*)d_ws;                       // 256 KB
    unsigned int* cnt    = (unsigned int*)((char*)d_ws + B_ * D0_ * sizeof(float)); // 512 B

    prep_kernel<<<B_, D0_, 0, stream>>>(enc, cur_idx, W, v, cnt);
    logits_fused_kernel<<<(B_ * N_) / 4, 256, 0, stream>>>(nb, v, out, cnt);
}

// Round 6
// 531.268 us; speedup vs baseline: 5.1920x; 5.1920x over previous
//
#include <hip/hip_runtime.h>
#include <hip/hip_bf16.h>
#include <math.h>

// Problem constants (from reference):
//   B=128, S=1024, D1=64 (SIZE1), N=2048, D0=512 (SIZE0)
#define B_   128
#define S_   1024
#define D1_  64
#define N_   2048
#define D0_  512

// R0 logits geometry (empirically fastest stream): block = 256 thr = 4 waves,
// one row per wave, 65536 one-shot blocks, 512 blocks per batch.
#define BLOCKS_PER_BATCH 512

// -----------------------------------------------------------------------------
// Kernel 0: v[b,s] = sum_d enc[b, current_index, d] * W[d, s]
// Bias dropped (per-row constant -> cancels in softmax). Also resets the
// per-batch completion counter with an agent-scope store so the logits
// kernel's MALL-side atomics observe 0 (d_ws is poisoned once, never
// re-poisoned between replays).
// -----------------------------------------------------------------------------
__global__ __launch_bounds__(D0_) void prep_kernel(
    const float* __restrict__ enc, const int* __restrict__ cur_idx,
    const float* __restrict__ W, float* __restrict__ v,
    unsigned int* __restrict__ cnt)
{
    __shared__ float temp[D1_];
    const int b = blockIdx.x;
    const int t = threadIdx.x;           // 0..511
    const int ci = *cur_idx;
    if (t == 0) {
        __hip_atomic_store(&cnt[b], 0u, __ATOMIC_RELAXED, __HIP_MEMORY_SCOPE_AGENT);
    }
    if (t < D1_) {
        temp[t] = enc[(size_t)b * (S_ * D1_) + (size_t)ci * D1_ + t];
    }
    __syncthreads();
    float acc = 0.f;
#pragma unroll
    for (int d = 0; d < D1_; ++d) {
        acc += temp[d] * W[d * D0_ + t];
    }
    v[b * D0_ + t] = acc;
}

// -----------------------------------------------------------------------------
// Kernel 1 (fused): logits + per-batch softmax finisher, NO cache-flush fences.
// Stream part is EXACTLY R0: one 64-lane wave per row, 2 coalesced float4 nb
// loads + 2 L2-hit v loads, 8 FMAs, 6-step butterfly, one logit store per
// wave. The logit store is a relaxed AGENT-scope atomic store (sc0 sc1,
// write-through to the MALL coherence point -> nothing dirty to flush).
// __syncthreads() drains vmcnt(0), ordering those stores before the relaxed
// atomicAdd on the batch counter. The 512th block of a batch re-reads the
// 2048 logits with agent-scope atomic loads (bypass L1/L2 -> MALL) and
// performs the softmax in place, overlapping the tail of the stream.
// -----------------------------------------------------------------------------
__global__ __launch_bounds__(256) void logits_fused_kernel(
    const float* __restrict__ nb, const float* __restrict__ v,
    float* __restrict__ out, unsigned int* __restrict__ cnt)
{
    const int wave = threadIdx.x >> 6;          // 0..3
    const int lane = threadIdx.x & 63;
    const size_t row = (size_t)blockIdx.x * 4 + wave;   // 0 .. B_*N_-1
    const int b = blockIdx.x >> 9;              // batch (block-uniform)

    const float4* __restrict__ r  = (const float4*)(nb + row * D0_);
    const float4* __restrict__ vv = (const float4*)(v + (size_t)b * D0_);

    float4 r0 = r[lane];
    float4 r1 = r[lane + 64];
    float4 v0 = vv[lane];
    float4 v1 = vv[lane + 64];

    float s = r0.x * v0.x + r0.y * v0.y + r0.z * v0.z + r0.w * v0.w
            + r1.x * v1.x + r1.y * v1.y + r1.z * v1.z + r1.w * v1.w;

#pragma unroll
    for (int off = 32; off; off >>= 1) s += __shfl_xor(s, off);

    if (lane == 0) {
        // write-through to coherence point; no L2 dirty state
        __hip_atomic_store(&out[row], s, __ATOMIC_RELAXED, __HIP_MEMORY_SCOPE_AGENT);
    }

    // ---- completion protocol (no cache writeback) ----
    __shared__ unsigned int prev;
    __syncthreads();                 // barrier drain: vmcnt(0) -> stores at MALL
    if (threadIdx.x == 0) {
        prev = atomicAdd(&cnt[b], 1u);   // relaxed, executes at MALL
    }
    __syncthreads();
    if (prev != BLOCKS_PER_BATCH - 1) return;   // not the last block of batch b

    // ---- finisher: softmax over out[b*N_ .. b*N_+N_) ----
    float* rowp = out + (size_t)b * N_;
    const int t = threadIdx.x;
    const int w2 = t >> 6, l2 = t & 63;

    float vals[8];
    float m = -INFINITY;
#pragma unroll
    for (int i = 0; i < 8; ++i) {
        // bypass L1/L2, read the coherence point
        vals[i] = __hip_atomic_load(&rowp[t + i * 256], __ATOMIC_RELAXED,
                                    __HIP_MEMORY_SCOPE_AGENT);
        m = fmaxf(m, vals[i]);
    }
#pragma unroll
    for (int off = 32; off; off >>= 1) m = fmaxf(m, __shfl_xor(m, off));

    __shared__ float redm[4];
    __shared__ float reds[4];
    if (l2 == 0) redm[w2] = m;
    __syncthreads();
    m = fmaxf(fmaxf(redm[0], redm[1]), fmaxf(redm[2], redm[3]));

    float sum = 0.f;
#pragma unroll
    for (int i = 0; i < 8; ++i) {
        vals[i] = __expf(vals[i] - m);
        sum += vals[i];
    }
#pragma unroll
    for (int off = 32; off; off >>= 1) sum += __shfl_xor(sum, off);
    if (l2 == 0) reds[w2] = sum;
    __syncthreads();
    sum = reds[0] + reds[1] + reds[2] + reds[3];

    const float inv = 1.0f / sum;
#pragma unroll
    for (int i = 0; i < 8; ++i) rowp[t + i * 256] = vals[i] * inv;
}

extern "C" void kernel_launch(void* const* d_in, const int* in_sizes, int n_in,
                              void* d_out, int out_size, void* d_ws, size_t ws_size,
                              hipStream_t stream)
{
    // Input order per setup_inputs():
    //   0: encoder_outputs          (B,S,D1) f32
    //   1: current_index            scalar int
    //   2: encoder_outputs_neighbor (B,N,D0) f32
    //   3: neighbor_num             scalar int (== N_, unused)
    //   4: W                        (D1,D0) f32
    //   5: b                        (D1,) f32  -- cancels in softmax, unused
    const float* enc     = (const float*)d_in[0];
    const int*   cur_idx = (const int*)d_in[1];
    const float* nb      = (const float*)d_in[2];
    const float* W       = (const float*)d_in[4];
    float*       out     = (float*)d_out;
    float*       v       = (float*)d_ws;                       // 256 KB
    unsigned int* cnt    = (unsigned int*)((char*)d_ws + B_ * D0_ * sizeof(float)); // 512 B

    prep_kernel<<<B_, D0_, 0, stream>>>(enc, cur_idx, W, v, cnt);
    logits_fused_kernel<<<(B_ * N_) / 4, 256, 0, stream>>>(nb, v, out, cnt);
}

// Round 7
// 99.670 us; speedup vs baseline: 27.6749x; 5.3303x over previous
//
#include <hip/hip_runtime.h>
#include <hip/hip_bf16.h>
#include <math.h>

// Problem constants (from reference):
//   B=128, S=1024, D1=64 (SIZE1), N=2048, D0=512 (SIZE0)
#define B_   128
#define S_   1024
#define D1_  64
#define N_   2048
#define D0_  512

// -----------------------------------------------------------------------------
// Kernel 0: v[b,s] = sum_d enc[b, current_index, d] * W[d, s]
// Bias dropped: adds a per-row constant to logits -> cancels in softmax.
// -----------------------------------------------------------------------------
__global__ __launch_bounds__(D0_) void prep_kernel(
    const float* __restrict__ enc, const int* __restrict__ cur_idx,
    const float* __restrict__ W, float* __restrict__ v)
{
    __shared__ float temp[D1_];
    const int b = blockIdx.x;
    const int t = threadIdx.x;           // 0..511
    const int ci = *cur_idx;
    if (t < D1_) {
        temp[t] = enc[(size_t)b * (S_ * D1_) + (size_t)ci * D1_ + t];
    }
    __syncthreads();
    float acc = 0.f;
#pragma unroll
    for (int d = 0; d < D1_; ++d) {
        acc += temp[d] * W[d * D0_ + t];
    }
    v[b * D0_ + t] = acc;
}

// -----------------------------------------------------------------------------
// Kernel 1: logits[b,n] = dot(neighbor[b,n,:], v[b,:])
// R0 structure (empirically fastest): one 64-lane wave per row, one-shot
// blocks of 4 waves, 6-step butterfly, lane-0 store. Single delta vs R0:
// v[b] is staged in LDS once per block and read via ds_read_b128
// (lane*16B consecutive -> 2-way bank aliasing = free), halving global-load
// instructions per wave (4 -> 2) and taking v off the vmem path.
// -----------------------------------------------------------------------------
__global__ __launch_bounds__(256) void logits_kernel(
    const float* __restrict__ nb, const float* __restrict__ v,
    float* __restrict__ out)
{
    __shared__ float4 vs[D0_ / 4];               // 2 KB
    const int t = threadIdx.x;
    const int wave = t >> 6;                     // 0..3
    const int lane = t & 63;
    const size_t row = (size_t)blockIdx.x * 4 + wave;   // 0 .. B_*N_-1
    const int b = blockIdx.x >> 9;               // 512 blocks per batch

    if (t < D0_ / 4) {
        vs[t] = ((const float4*)(v + (size_t)b * D0_))[t];
    }
    __syncthreads();

    const float4* __restrict__ r = (const float4*)(nb + row * D0_);

    float4 r0 = r[lane];
    float4 r1 = r[lane + 64];
    float4 v0 = vs[lane];
    float4 v1 = vs[lane + 64];

    float s = r0.x * v0.x + r0.y * v0.y + r0.z * v0.z + r0.w * v0.w
            + r1.x * v1.x + r1.y * v1.y + r1.z * v1.z + r1.w * v1.w;

#pragma unroll
    for (int off = 32; off; off >>= 1) s += __shfl_xor(s, off);

    if (lane == 0) out[row] = s;
}

// -----------------------------------------------------------------------------
// Kernel 2: in-place row softmax over N_=2048 elements. 128 blocks (one per
// batch) x 256 threads; each thread owns 8 elements.
// -----------------------------------------------------------------------------
__global__ __launch_bounds__(256) void softmax_kernel(float* __restrict__ out)
{
    float* row = out + (size_t)blockIdx.x * N_;
    const int t = threadIdx.x;
    const int wave = t >> 6, lane = t & 63;

    float vals[8];
    float m = -INFINITY;
#pragma unroll
    for (int i = 0; i < 8; ++i) {
        vals[i] = row[t + i * 256];
        m = fmaxf(m, vals[i]);
    }
#pragma unroll
    for (int off = 32; off; off >>= 1) m = fmaxf(m, __shfl_xor(m, off));

    __shared__ float redm[4];
    __shared__ float reds[4];
    if (lane == 0) redm[wave] = m;
    __syncthreads();
    m = fmaxf(fmaxf(redm[0], redm[1]), fmaxf(redm[2], redm[3]));

    float s = 0.f;
#pragma unroll
    for (int i = 0; i < 8; ++i) {
        vals[i] = __expf(vals[i] - m);
        s += vals[i];
    }
#pragma unroll
    for (int off = 32; off; off >>= 1) s += __shfl_xor(s, off);
    if (lane == 0) reds[wave] = s;
    __syncthreads();
    s = reds[0] + reds[1] + reds[2] + reds[3];

    const float inv = 1.0f / s;
#pragma unroll
    for (int i = 0; i < 8; ++i) row[t + i * 256] = vals[i] * inv;
}

extern "C" void kernel_launch(void* const* d_in, const int* in_sizes, int n_in,
                              void* d_out, int out_size, void* d_ws, size_t ws_size,
                              hipStream_t stream)
{
    // Input order per setup_inputs():
    //   0: encoder_outputs          (B,S,D1) f32
    //   1: current_index            scalar int
    //   2: encoder_outputs_neighbor (B,N,D0) f32
    //   3: neighbor_num             scalar int (== N_, unused)
    //   4: W                        (D1,D0) f32
    //   5: b                        (D1,) f32  -- cancels in softmax, unused
    const float* enc     = (const float*)d_in[0];
    const int*   cur_idx = (const int*)d_in[1];
    const float* nb      = (const float*)d_in[2];
    const float* W       = (const float*)d_in[4];
    float*       out     = (float*)d_out;
    float*       v       = (float*)d_ws;   // B_*D0_*4 = 256 KB scratch

    prep_kernel<<<B_, D0_, 0, stream>>>(enc, cur_idx, W, v);
    logits_kernel<<<(B_ * N_) / 4, 256, 0, stream>>>(nb, v, out);
    softmax_kernel<<<B_, 256, 0, stream>>>(out);
}

// Round 8
// 95.050 us; speedup vs baseline: 29.0199x; 1.0486x over previous
//
#include <hip/hip_runtime.h>
#include <hip/hip_bf16.h>
#include <math.h>

// Problem constants (from reference):
//   B=128, S=1024, D1=64 (SIZE1), N=2048, D0=512 (SIZE0)
#define B_   128
#define S_   1024
#define D1_  64
#define N_   2048
#define D0_  512

// -----------------------------------------------------------------------------
// Kernel 0: v[b,s] = sum_d enc[b, current_index, d] * W[d, s]
// Bias dropped: adds a per-row constant to logits -> cancels in softmax.
// -----------------------------------------------------------------------------
__global__ __launch_bounds__(D0_) void prep_kernel(
    const float* __restrict__ enc, const int* __restrict__ cur_idx,
    const float* __restrict__ W, float* __restrict__ v)
{
    __shared__ float temp[D1_];
    const int b = blockIdx.x;
    const int t = threadIdx.x;           // 0..511
    const int ci = *cur_idx;
    if (t < D1_) {
        temp[t] = enc[(size_t)b * (S_ * D1_) + (size_t)ci * D1_ + t];
    }
    __syncthreads();
    float acc = 0.f;
#pragma unroll
    for (int d = 0; d < D1_; ++d) {
        acc += temp[d] * W[d * D0_ + t];
    }
    v[b * D0_ + t] = acc;
}

// -----------------------------------------------------------------------------
// Kernel 1: logits[b,n] = dot(neighbor[b,n,:], v[b,:])  (512-long dot)
// Empirically fastest structure (R0, 95.1 us): one 64-lane wave per row,
// one-shot blocks of 4 waves. Per row: 2 coalesced float4 nb loads (the HBM
// stream), 2 v loads (L1/L2 hits, free — verified by R6/R7 ablation),
// 8 FMAs, 6-step butterfly, lane-0 store. 65536 blocks saturate the
// delivered-read path at ~6.06 TB/s (96% of m13's 6.29 TB/s ceiling).
// -----------------------------------------------------------------------------
__global__ __launch_bounds__(256) void logits_kernel(
    const float* __restrict__ nb, const float* __restrict__ v,
    float* __restrict__ out)
{
    const int wave = threadIdx.x >> 6;          // 0..3
    const int lane = threadIdx.x & 63;
    const size_t row = (size_t)blockIdx.x * 4 + wave;   // 0 .. B_*N_-1
    const int b = (int)(row >> 11);             // row / N_
    const float4* __restrict__ r = (const float4*)(nb + row * D0_);
    const float4* __restrict__ vv = (const float4*)(v + (size_t)b * D0_);

    float4 r0 = r[lane];
    float4 r1 = r[lane + 64];
    float4 v0 = vv[lane];
    float4 v1 = vv[lane + 64];

    float s = r0.x * v0.x + r0.y * v0.y + r0.z * v0.z + r0.w * v0.w
            + r1.x * v1.x + r1.y * v1.y + r1.z * v1.z + r1.w * v1.w;

#pragma unroll
    for (int off = 32; off; off >>= 1) s += __shfl_xor(s, off);

    if (lane == 0) out[row] = s;
}

// -----------------------------------------------------------------------------
// Kernel 2: in-place row softmax over N_=2048 elements. 128 blocks (one per
// batch) x 256 threads; each thread owns 8 elements.
// -----------------------------------------------------------------------------
__global__ __launch_bounds__(256) void softmax_kernel(float* __restrict__ out)
{
    float* row = out + (size_t)blockIdx.x * N_;
    const int t = threadIdx.x;
    const int wave = t >> 6, lane = t & 63;

    float vals[8];
    float m = -INFINITY;
#pragma unroll
    for (int i = 0; i < 8; ++i) {
        vals[i] = row[t + i * 256];
        m = fmaxf(m, vals[i]);
    }
#pragma unroll
    for (int off = 32; off; off >>= 1) m = fmaxf(m, __shfl_xor(m, off));

    __shared__ float redm[4];
    __shared__ float reds[4];
    if (lane == 0) redm[wave] = m;
    __syncthreads();
    m = fmaxf(fmaxf(redm[0], redm[1]), fmaxf(redm[2], redm[3]));

    float s = 0.f;
#pragma unroll
    for (int i = 0; i < 8; ++i) {
        vals[i] = __expf(vals[i] - m);
        s += vals[i];
    }
#pragma unroll
    for (int off = 32; off; off >>= 1) s += __shfl_xor(s, off);
    if (lane == 0) reds[wave] = s;
    __syncthreads();
    s = reds[0] + reds[1] + reds[2] + reds[3];

    const float inv = 1.0f / s;
#pragma unroll
    for (int i = 0; i < 8; ++i) row[t + i * 256] = vals[i] * inv;
}

extern "C" void kernel_launch(void* const* d_in, const int* in_sizes, int n_in,
                              void* d_out, int out_size, void* d_ws, size_t ws_size,
                              hipStream_t stream)
{
    // Input order per setup_inputs():
    //   0: encoder_outputs          (B,S,D1) f32
    //   1: current_index            scalar int
    //   2: encoder_outputs_neighbor (B,N,D0) f32
    //   3: neighbor_num             scalar int (== N_, unused)
    //   4: W                        (D1,D0) f32
    //   5: b                        (D1,) f32  -- cancels in softmax, unused
    const float* enc     = (const float*)d_in[0];
    const int*   cur_idx = (const int*)d_in[1];
    const float* nb      = (const float*)d_in[2];
    const float* W       = (const float*)d_in[4];
    float*       out     = (float*)d_out;
    float*       v       = (float*)d_ws;   // B_*D0_*4 = 256 KB scratch

    prep_kernel<<<B_, D0_, 0, stream>>>(enc, cur_idx, W, v);
    logits_kernel<<<(B_ * N_) / 4, 256, 0, stream>>>(nb, v, out);
    softmax_kernel<<<B_, 256, 0, stream>>>(out);
}